// Round 14
// baseline (81.056 us; speedup 1.0000x reference)
//
#include <hip/hip_runtime.h>

#define RES_UP 224
#define RES_DN 8
#define T2D_N (RES_UP * RES_UP)           // 50176 texels
#define T3D_N (RES_DN * RES_DN * RES_DN)  // 512 cells

__device__ __forceinline__ float fracf(float t) { return t - floorf(t); }

// ---- 2D table: 10-bit quant, full 2x2 footprint per texel ----
__device__ __forceinline__ uint32_t q3w(const float* p) {
    uint32_t q0 = (uint32_t)(fracf(p[0]) * 1023.0f + 0.5f);
    uint32_t q1 = (uint32_t)(fracf(p[1]) * 1023.0f + 0.5f);
    uint32_t q2 = (uint32_t)(fracf(p[2]) * 1023.0f + 0.5f);
    return q0 | (q1 << 10) | (q2 << 20);
}

__global__ __launch_bounds__(256) void repack2d_q(const float* __restrict__ t2d,
                                                  uint4* __restrict__ pk) {
    int i = blockIdx.x * blockDim.x + threadIdx.x;
    if (i >= T2D_N) return;
    int u = i / RES_UP;
    int v = i - u * RES_UP;
    int un = min(u + 1, RES_UP - 1);
    int vn = min(v + 1, RES_UP - 1);
    uint4 t;
    t.x = q3w(t2d + ((size_t)u  * RES_UP + v ) * 3);
    t.y = q3w(t2d + ((size_t)u  * RES_UP + vn) * 3);
    t.z = q3w(t2d + ((size_t)un * RES_UP + v ) * 3);
    t.w = q3w(t2d + ((size_t)un * RES_UP + vn) * 3);
    pk[i] = t;
}

// ---- 3D table: 8-bit channel-major footprint, both a-planes ----
__global__ __launch_bounds__(256) void repack3d_q(const float* __restrict__ t3d,
                                                  uint4* __restrict__ pk3) {
    int i = blockIdx.x * blockDim.x + threadIdx.x;
    if (i >= T3D_N) return;
    int a = i >> 6, b = (i >> 3) & 7, c = i & 7;
    int an = min(a + 1, 7), bn = min(b + 1, 7), cn = min(c + 1, 7);
    uint4 A, B;
    uint32_t* Aw = &A.x;
    uint32_t* Bw = &B.x;
    #pragma unroll
    for (int l = 0; l < 3; ++l) {
        uint32_t a00 = (uint32_t)(fracf(t3d[(((a  * 8) + b ) * 8 + c ) * 3 + l]) * 255.0f + 0.5f);
        uint32_t a01 = (uint32_t)(fracf(t3d[(((a  * 8) + b ) * 8 + cn) * 3 + l]) * 255.0f + 0.5f);
        uint32_t a10 = (uint32_t)(fracf(t3d[(((a  * 8) + bn) * 8 + c ) * 3 + l]) * 255.0f + 0.5f);
        uint32_t a11 = (uint32_t)(fracf(t3d[(((a  * 8) + bn) * 8 + cn) * 3 + l]) * 255.0f + 0.5f);
        uint32_t b00 = (uint32_t)(fracf(t3d[(((an * 8) + b ) * 8 + c ) * 3 + l]) * 255.0f + 0.5f);
        uint32_t b01 = (uint32_t)(fracf(t3d[(((an * 8) + b ) * 8 + cn) * 3 + l]) * 255.0f + 0.5f);
        uint32_t b10 = (uint32_t)(fracf(t3d[(((an * 8) + bn) * 8 + c ) * 3 + l]) * 255.0f + 0.5f);
        uint32_t b11 = (uint32_t)(fracf(t3d[(((an * 8) + bn) * 8 + cn) * 3 + l]) * 255.0f + 0.5f);
        Aw[l] = a00 | (a01 << 8) | (a10 << 16) | (a11 << 24);
        Bw[l] = b00 | (b01 << 8) | (b10 << 16) | (b11 << 24);
    }
    A.w = 0; B.w = 0;
    pk3[i] = A;
    pk3[i + T3D_N] = B;
}

__device__ __forceinline__ float uq10(uint32_t w, int s) {
    return (float)((w >> s) & 1023u);
}
__device__ __forceinline__ float ub(uint32_t w, int k) {
    return (float)((w >> (k * 8)) & 255u);
}

// =================== Stage A: x -> packed {cell, fractions} key ===================
// Chain: coalesced x read -> one divergent gather -> bilinear -> coalesced u32 write.
__global__ __launch_bounds__(512) void stageA(
    const float* __restrict__ x,
    const uint4* __restrict__ t2,
    uint32_t* __restrict__ keys,
    int npts)
{
    int q = blockIdx.x * 512 + threadIdx.x;
    if (q >= npts) return;

    const float2 xv = ((const float2*)x)[q];
    float u = xv.x * (float)(RES_UP - 1);
    float v = xv.y * (float)(RES_UP - 1);
    int u0 = (int)u;
    int v0 = (int)v;
    float fu = u - (float)u0;
    float fv = v - (float)v0;

    uint4 g = t2[u0 * RES_UP + v0];

    const float S = (float)(RES_DN - 1) / 1023.0f;
    float wu0 = 1.0f - fu, wv0 = 1.0f - fv;
    float r00 = wu0 * wv0, r01 = wu0 * fv;
    float r10 = fu * wv0,  r11 = fu * fv;
    float key[3];
    #pragma unroll
    for (int l = 0; l < 3; ++l) {
        int s = l * 10;
        float d = uq10(g.x, s) * r00;
        d = fmaf(uq10(g.y, s), r01, d);
        d = fmaf(uq10(g.z, s), r10, d);
        d = fmaf(uq10(g.w, s), r11, d);
        key[l] = d * S;   // [0, 7]
    }
    int a0 = min((int)key[0], RES_DN - 2);
    int b0 = min((int)key[1], RES_DN - 2);
    int c0 = min((int)key[2], RES_DN - 2);
    float fa = key[0] - (float)a0;
    float fb = key[1] - (float)b0;
    float fc = key[2] - (float)c0;
    uint32_t si  = (uint32_t)((a0 * RES_DN + b0) * RES_DN + c0);       // 9 bits
    uint32_t fa8 = (uint32_t)(fa * 255.0f + 0.5f);                     // 8 bits
    uint32_t fb8 = (uint32_t)(fb * 255.0f + 0.5f);                     // 8 bits
    uint32_t fc7 = (uint32_t)(fc * 127.0f + 0.5f);                     // 7 bits

    keys[q] = si | (fa8 << 9) | (fb8 << 17) | (fc7 << 25);
}

// =================== Stage B: key -> trilinear -> out ===================
// Chain: coalesced key read -> 2 LDS reads -> byte-dot trilinear -> store.
__global__ __launch_bounds__(512) void stageB(
    const uint32_t* __restrict__ keys,
    const uint4* __restrict__ t3p,
    float* __restrict__ out,
    int npts)
{
    __shared__ uint4 s3[2 * T3D_N];
    #pragma unroll
    for (int i = threadIdx.x; i < 2 * T3D_N; i += 512) s3[i] = t3p[i];
    __syncthreads();

    int q = blockIdx.x * 512 + threadIdx.x;
    if (q >= npts) return;

    uint32_t k = keys[q];
    int si = (int)(k & 511u);
    float fa = (float)((k >> 9)  & 255u) * (1.0f / 255.0f);
    float fb = (float)((k >> 17) & 255u) * (1.0f / 255.0f);
    float fc = (float)((k >> 25) & 127u) * (1.0f / 127.0f);

    uint4 qA = s3[si];
    uint4 qB = s3[si + T3D_N];

    const float D = 1.0f / 255.0f;
    float wb0 = 1.0f - fb, wc0 = 1.0f - fc;
    float q00 = wb0 * wc0, q01 = wb0 * fc;
    float q10 = fb * wc0,  q11 = fb * fc;
    float wa0D = (1.0f - fa) * D;
    float faD  = fa * D;
    const uint32_t* Aw = &qA.x;
    const uint32_t* Bw = &qB.x;
    float r[3];
    #pragma unroll
    for (int l = 0; l < 3; ++l) {
        uint32_t wA = Aw[l], wB = Bw[l];
        float dA = ub(wA, 0) * q00;
        dA = fmaf(ub(wA, 1), q01, dA);
        dA = fmaf(ub(wA, 2), q10, dA);
        dA = fmaf(ub(wA, 3), q11, dA);
        float dB = ub(wB, 0) * q00;
        dB = fmaf(ub(wB, 1), q01, dB);
        dB = fmaf(ub(wB, 2), q10, dB);
        dB = fmaf(ub(wB, 3), q11, dB);
        r[l] = wa0D * dA + faD * dB;
    }

    float* o = out + (size_t)q * 3;
    o[0] = r[0];
    o[1] = r[1];
    o[2] = r[2];
}

// ======================= r10 fused kernel (fallback when ws is small) =======================
__global__ __launch_bounds__(512) void fused_1pt(
    const float* __restrict__ x,
    const uint4* __restrict__ t2,
    const uint4* __restrict__ t3p,
    float* __restrict__ out,
    int npts)
{
    __shared__ uint4 s3[2 * T3D_N];
    #pragma unroll
    for (int i = threadIdx.x; i < 2 * T3D_N; i += 512) s3[i] = t3p[i];
    __syncthreads();

    int q = blockIdx.x * 512 + threadIdx.x;
    if (q >= npts) return;

    const float2 xv = ((const float2*)x)[q];
    float u = xv.x * (float)(RES_UP - 1);
    float v = xv.y * (float)(RES_UP - 1);
    int u0 = (int)u;
    int v0 = (int)v;
    float fu = u - (float)u0;
    float fv = v - (float)v0;

    uint4 g = t2[u0 * RES_UP + v0];

    const float S = (float)(RES_DN - 1) / 1023.0f;
    float wu0 = 1.0f - fu, wv0 = 1.0f - fv;
    float r00 = wu0 * wv0, r01 = wu0 * fv;
    float r10 = fu * wv0,  r11 = fu * fv;
    float key[3];
    #pragma unroll
    for (int l = 0; l < 3; ++l) {
        int s = l * 10;
        float d = uq10(g.x, s) * r00;
        d = fmaf(uq10(g.y, s), r01, d);
        d = fmaf(uq10(g.z, s), r10, d);
        d = fmaf(uq10(g.w, s), r11, d);
        key[l] = d * S;
    }
    int a0 = min((int)key[0], RES_DN - 2);
    int b0 = min((int)key[1], RES_DN - 2);
    int c0 = min((int)key[2], RES_DN - 2);
    float fa = key[0] - (float)a0;
    float fb = key[1] - (float)b0;
    float fc = key[2] - (float)c0;
    int si = (a0 * RES_DN + b0) * RES_DN + c0;

    uint4 qA = s3[si];
    uint4 qB = s3[si + T3D_N];

    const float D = 1.0f / 255.0f;
    float wb0 = 1.0f - fb, wc0 = 1.0f - fc;
    float q00 = wb0 * wc0, q01 = wb0 * fc;
    float q10 = fb * wc0,  q11 = fb * fc;
    float wa0D = (1.0f - fa) * D;
    float faD  = fa * D;
    const uint32_t* Aw = &qA.x;
    const uint32_t* Bw = &qB.x;
    float r[3];
    #pragma unroll
    for (int l = 0; l < 3; ++l) {
        uint32_t wA = Aw[l], wB = Bw[l];
        float dA = ub(wA, 0) * q00;
        dA = fmaf(ub(wA, 1), q01, dA);
        dA = fmaf(ub(wA, 2), q10, dA);
        dA = fmaf(ub(wA, 3), q11, dA);
        float dB = ub(wB, 0) * q00;
        dB = fmaf(ub(wB, 1), q01, dB);
        dB = fmaf(ub(wB, 2), q10, dB);
        dB = fmaf(ub(wB, 3), q11, dB);
        r[l] = wa0D * dA + faD * dB;
    }

    float* o = out + (size_t)q * 3;
    o[0] = r[0];
    o[1] = r[1];
    o[2] = r[2];
}

// Fallback (pure f32, unpacked tables) if workspace is tiny.
__device__ __forceinline__ float4 lerp4(const float4 a, const float4 b, const float t) {
    const float s = 1.0f - t;
    return make_float4(a.x * s + b.x * t, a.y * s + b.y * t, a.z * s + b.z * t, 0.0f);
}

__global__ __launch_bounds__(256) void fused_fallback(
    const float* __restrict__ x,
    const float* __restrict__ t2d,
    const float* __restrict__ t3d,
    float* __restrict__ out,
    int nquad)
{
    __shared__ float4 s3d[T3D_N];
    for (int i = threadIdx.x; i < T3D_N; i += blockDim.x) {
        float a = t3d[i * 3 + 0];
        float b = t3d[i * 3 + 1];
        float c = t3d[i * 3 + 2];
        s3d[i] = make_float4(fracf(a), fracf(b), fracf(c), 0.0f);
    }
    __syncthreads();

    const int stride = gridDim.x * blockDim.x;
    for (int q = blockIdx.x * blockDim.x + threadIdx.x; q < nquad; q += stride) {
        const float4 xa = ((const float4*)x)[q * 2 + 0];
        const float4 xb = ((const float4*)x)[q * 2 + 1];
        const float px[4] = {xa.x, xa.z, xb.x, xb.z};
        const float py[4] = {xa.y, xa.w, xb.y, xb.w};
        float res[12];

        #pragma unroll
        for (int k = 0; k < 4; ++k) {
            float u = px[k] * (float)(RES_UP - 1);
            float v = py[k] * (float)(RES_UP - 1);
            int u0 = min(max((int)floorf(u), 0), RES_UP - 2);
            int v0 = min(max((int)floorf(v), 0), RES_UP - 2);
            float fuu = u - (float)u0;
            float fvv = v - (float)v0;

            const float* p00 = t2d + ((size_t)u0 * RES_UP + v0) * 3;
            const float* p10 = p00 + RES_UP * 3;
            float key[3];
            #pragma unroll
            for (int l = 0; l < 3; ++l) {
                float c00 = fracf(p00[l]);
                float c01 = fracf(p00[3 + l]);
                float c10 = fracf(p10[l]);
                float c11 = fracf(p10[3 + l]);
                float c0 = c00 * (1.0f - fvv) + c01 * fvv;
                float c1 = c10 * (1.0f - fvv) + c11 * fvv;
                key[l] = c0 * (1.0f - fuu) + c1 * fuu;
            }

            float uu = key[0] * (float)(RES_DN - 1);
            float vv = key[1] * (float)(RES_DN - 1);
            float ww = key[2] * (float)(RES_DN - 1);
            int a0 = min(max((int)floorf(uu), 0), RES_DN - 2);
            int b0 = min(max((int)floorf(vv), 0), RES_DN - 2);
            int c0 = min(max((int)floorf(ww), 0), RES_DN - 2);
            float fa = uu - (float)a0;
            float fb = vv - (float)b0;
            float fc = ww - (float)c0;

            int sidx = (a0 * RES_DN + b0) * RES_DN + c0;
            float4 e00 = lerp4(s3d[sidx], s3d[sidx + 1], fc);
            float4 e01 = lerp4(s3d[sidx + RES_DN], s3d[sidx + RES_DN + 1], fc);
            float4 e10 = lerp4(s3d[sidx + 64], s3d[sidx + 65], fc);
            float4 e11 = lerp4(s3d[sidx + 72], s3d[sidx + 73], fc);
            float4 e = lerp4(lerp4(e00, e01, fb), lerp4(e10, e11, fb), fa);

            res[k * 3 + 0] = e.x;
            res[k * 3 + 1] = e.y;
            res[k * 3 + 2] = e.z;
        }

        float4* o = (float4*)(out + (size_t)q * 12);
        o[0] = make_float4(res[0], res[1], res[2],  res[3]);
        o[1] = make_float4(res[4], res[5], res[6],  res[7]);
        o[2] = make_float4(res[8], res[9], res[10], res[11]);
    }
}

extern "C" void kernel_launch(void* const* d_in, const int* in_sizes, int n_in,
                              void* d_out, int out_size, void* d_ws, size_t ws_size,
                              hipStream_t stream) {
    const float* x   = (const float*)d_in[0];
    const float* t2d = (const float*)d_in[1];
    const float* t3d = (const float*)d_in[2];
    float* out = (float*)d_out;

    int npts  = in_sizes[0] / 2;
    int nquad = npts / 4;

    const size_t tbl_need   = (size_t)(T2D_N + 2 * T3D_N) * sizeof(uint4);   // 819200 B
    const size_t split_need = tbl_need + (size_t)npts * sizeof(uint32_t);    // + 33.5 MB

    if (ws_size >= tbl_need) {
        uint4* ws2 = (uint4*)d_ws;
        uint4* ws3 = ws2 + T2D_N;
        repack2d_q<<<(T2D_N + 255) / 256, 256, 0, stream>>>(t2d, ws2);
        repack3d_q<<<(T3D_N + 255) / 256, 256, 0, stream>>>(t3d, ws3);

        int grid = (npts + 511) / 512;
        if (ws_size >= split_need) {
            uint32_t* keys = (uint32_t*)(ws3 + 2 * T3D_N);
            stageA<<<grid, 512, 0, stream>>>(x, ws2, keys, npts);
            stageB<<<grid, 512, 0, stream>>>(keys, ws3, out, npts);
        } else {
            fused_1pt<<<grid, 512, 0, stream>>>(x, ws2, ws3, out, npts);
        }
    } else {
        fused_fallback<<<2048, 256, 0, stream>>>(x, t2d, t3d, out, nquad);
    }
}

// Round 15
// 59.197 us; speedup vs baseline: 1.3692x; 1.3692x over previous
//
#include <hip/hip_runtime.h>

#define RES_UP 224
#define RES_DN 8
#define T2D_N (RES_UP * RES_UP)           // 50176 texels
#define T3D_N (RES_DN * RES_DN * RES_DN)  // 512 cells

typedef uint32_t u32x4 __attribute__((ext_vector_type(4)));

__device__ __forceinline__ float fracf(float t) { return t - floorf(t); }

__device__ __forceinline__ uint32_t q3w(const float* p) {
    uint32_t q0 = (uint32_t)(fracf(p[0]) * 1023.0f + 0.5f);
    uint32_t q1 = (uint32_t)(fracf(p[1]) * 1023.0f + 0.5f);
    uint32_t q2 = (uint32_t)(fracf(p[2]) * 1023.0f + 0.5f);
    return q0 | (q1 << 10) | (q2 << 20);
}

// ---- merged repack: blocks 0..195 pack the 2D table (196*256 == 50176 exactly),
// ---- block 196 packs the 3D table (both a-planes). One launch instead of two.
__global__ __launch_bounds__(256) void repack_all(const float* __restrict__ t2d,
                                                  const float* __restrict__ t3d,
                                                  uint4* __restrict__ pk2,
                                                  uint4* __restrict__ pk3) {
    if (blockIdx.x < 196) {
        int i = blockIdx.x * 256 + threadIdx.x;   // < T2D_N by construction
        int u = i / RES_UP;
        int v = i - u * RES_UP;
        int un = min(u + 1, RES_UP - 1);
        int vn = min(v + 1, RES_UP - 1);
        uint4 t;
        t.x = q3w(t2d + ((size_t)u  * RES_UP + v ) * 3);
        t.y = q3w(t2d + ((size_t)u  * RES_UP + vn) * 3);
        t.z = q3w(t2d + ((size_t)un * RES_UP + v ) * 3);
        t.w = q3w(t2d + ((size_t)un * RES_UP + vn) * 3);
        pk2[i] = t;
    } else {
        for (int i = threadIdx.x; i < T3D_N; i += 256) {
            int a = i >> 6, b = (i >> 3) & 7, c = i & 7;
            int an = min(a + 1, 7), bn = min(b + 1, 7), cn = min(c + 1, 7);
            uint4 A, B;
            uint32_t* Aw = &A.x;
            uint32_t* Bw = &B.x;
            #pragma unroll
            for (int l = 0; l < 3; ++l) {
                uint32_t a00 = (uint32_t)(fracf(t3d[(((a  * 8) + b ) * 8 + c ) * 3 + l]) * 255.0f + 0.5f);
                uint32_t a01 = (uint32_t)(fracf(t3d[(((a  * 8) + b ) * 8 + cn) * 3 + l]) * 255.0f + 0.5f);
                uint32_t a10 = (uint32_t)(fracf(t3d[(((a  * 8) + bn) * 8 + c ) * 3 + l]) * 255.0f + 0.5f);
                uint32_t a11 = (uint32_t)(fracf(t3d[(((a  * 8) + bn) * 8 + cn) * 3 + l]) * 255.0f + 0.5f);
                uint32_t b00 = (uint32_t)(fracf(t3d[(((an * 8) + b ) * 8 + c ) * 3 + l]) * 255.0f + 0.5f);
                uint32_t b01 = (uint32_t)(fracf(t3d[(((an * 8) + b ) * 8 + cn) * 3 + l]) * 255.0f + 0.5f);
                uint32_t b10 = (uint32_t)(fracf(t3d[(((an * 8) + bn) * 8 + c ) * 3 + l]) * 255.0f + 0.5f);
                uint32_t b11 = (uint32_t)(fracf(t3d[(((an * 8) + bn) * 8 + cn) * 3 + l]) * 255.0f + 0.5f);
                Aw[l] = a00 | (a01 << 8) | (a10 << 16) | (a11 << 24);
                Bw[l] = b00 | (b01 << 8) | (b10 << 16) | (b11 << 24);
            }
            A.w = 0; B.w = 0;
            pk3[i] = A;
            pk3[i + T3D_N] = B;
        }
    }
}

__device__ __forceinline__ float uq10(uint32_t w, int s) {
    return (float)((w >> s) & 1023u);
}
__device__ __forceinline__ float ub(uint32_t w, int k) {
    return (float)((w >> (k * 8)) & 255u);
}

// ====== 4 pts/thread; volatile gathers pin issue order, compiler emits
// ====== counted vmcnt staircase waits before each consumer (r13, best: 61.3us). ======
__global__ __launch_bounds__(512) void fused_mlp4(
    const float* __restrict__ x,
    const uint4* __restrict__ t2,
    const uint4* __restrict__ t3p,
    float* __restrict__ out,
    int nth)   // total threads; npts == 4*nth
{
    __shared__ uint4 s3[2 * T3D_N];
    #pragma unroll
    for (int i = threadIdx.x; i < 2 * T3D_N; i += 512) s3[i] = t3p[i];
    __syncthreads();

    const int tid = blockIdx.x * 512 + threadIdx.x;

    const float2* X = (const float2*)x;
    const float2 xv0 = X[tid];
    const float2 xv1 = X[tid + nth];
    const float2 xv2 = X[tid + 2 * nth];
    const float2 xv3 = X[tid + 3 * nth];

    float uf0 = xv0.x * (float)(RES_UP - 1), vf0 = xv0.y * (float)(RES_UP - 1);
    float uf1 = xv1.x * (float)(RES_UP - 1), vf1 = xv1.y * (float)(RES_UP - 1);
    float uf2 = xv2.x * (float)(RES_UP - 1), vf2 = xv2.y * (float)(RES_UP - 1);
    float uf3 = xv3.x * (float)(RES_UP - 1), vf3 = xv3.y * (float)(RES_UP - 1);
    int iu0 = (int)uf0, iv0 = (int)vf0;
    int iu1 = (int)uf1, iv1 = (int)vf1;
    int iu2 = (int)uf2, iv2 = (int)vf2;
    int iu3 = (int)uf3, iv3 = (int)vf3;
    float fu0 = uf0 - (float)iu0, fv0 = vf0 - (float)iv0;
    float fu1 = uf1 - (float)iu1, fv1 = vf1 - (float)iv1;
    float fu2 = uf2 - (float)iu2, fv2 = vf2 - (float)iv2;
    float fu3 = uf3 - (float)iu3, fv3 = vf3 - (float)iv3;

    const volatile u32x4* T = (const volatile u32x4*)t2;
    u32x4 g0 = T[iu0 * RES_UP + iv0];
    u32x4 g1 = T[iu1 * RES_UP + iv1];
    u32x4 g2 = T[iu2 * RES_UP + iv2];
    u32x4 g3 = T[iu3 * RES_UP + iv3];

    const float S = (float)(RES_DN - 1) / 1023.0f;
    const float D = 1.0f / 255.0f;
    float r0[3], r1[3], r2[3], r3[3];

#define COMPUTE(G, FU, FV, R) do {                                              \
    float _wu0 = 1.0f - FU, _wv0 = 1.0f - FV;                                   \
    float _r00 = _wu0 * _wv0, _r01 = _wu0 * FV;                                 \
    float _r10 = FU * _wv0,   _r11 = FU * FV;                                   \
    float _key[3];                                                              \
    _Pragma("unroll")                                                           \
    for (int l = 0; l < 3; ++l) {                                               \
        int _s = l * 10;                                                        \
        float _d = uq10(G.x, _s) * _r00;                                        \
        _d = fmaf(uq10(G.y, _s), _r01, _d);                                     \
        _d = fmaf(uq10(G.z, _s), _r10, _d);                                     \
        _d = fmaf(uq10(G.w, _s), _r11, _d);                                     \
        _key[l] = _d * S;                                                       \
    }                                                                           \
    int _a0 = min((int)_key[0], RES_DN - 2);                                    \
    int _b0 = min((int)_key[1], RES_DN - 2);                                    \
    int _c0 = min((int)_key[2], RES_DN - 2);                                    \
    float _fa = _key[0] - (float)_a0;                                           \
    float _fb = _key[1] - (float)_b0;                                           \
    float _fc = _key[2] - (float)_c0;                                           \
    int _si = (_a0 * RES_DN + _b0) * RES_DN + _c0;                              \
    uint4 _qA = s3[_si];                                                        \
    uint4 _qB = s3[_si + T3D_N];                                                \
    float _wb0 = 1.0f - _fb, _wc0 = 1.0f - _fc;                                 \
    float _q00 = _wb0 * _wc0, _q01 = _wb0 * _fc;                                \
    float _q10 = _fb * _wc0,  _q11 = _fb * _fc;                                 \
    float _wa0D = (1.0f - _fa) * D;                                             \
    float _faD  = _fa * D;                                                      \
    const uint32_t* _Aw = &_qA.x;                                               \
    const uint32_t* _Bw = &_qB.x;                                               \
    _Pragma("unroll")                                                           \
    for (int l = 0; l < 3; ++l) {                                               \
        uint32_t _wA = _Aw[l], _wB = _Bw[l];                                    \
        float _dA = ub(_wA, 0) * _q00;                                          \
        _dA = fmaf(ub(_wA, 1), _q01, _dA);                                      \
        _dA = fmaf(ub(_wA, 2), _q10, _dA);                                      \
        _dA = fmaf(ub(_wA, 3), _q11, _dA);                                      \
        float _dB = ub(_wB, 0) * _q00;                                          \
        _dB = fmaf(ub(_wB, 1), _q01, _dB);                                      \
        _dB = fmaf(ub(_wB, 2), _q10, _dB);                                      \
        _dB = fmaf(ub(_wB, 3), _q11, _dB);                                      \
        R[l] = _wa0D * _dA + _faD * _dB;                                        \
    }                                                                           \
} while (0)

    COMPUTE(g0, fu0, fv0, r0);   // vmcnt(3): g1..g3 still in flight
    COMPUTE(g1, fu1, fv1, r1);   // vmcnt(2)
    COMPUTE(g2, fu2, fv2, r2);   // vmcnt(1)
    COMPUTE(g3, fu3, fv3, r3);   // vmcnt(0)

    float* o0 = out + (size_t)tid * 3;
    o0[0] = r0[0]; o0[1] = r0[1]; o0[2] = r0[2];
    float* o1 = out + ((size_t)tid + nth) * 3;
    o1[0] = r1[0]; o1[1] = r1[1]; o1[2] = r1[2];
    float* o2 = out + ((size_t)tid + 2 * (size_t)nth) * 3;
    o2[0] = r2[0]; o2[1] = r2[1]; o2[2] = r2[2];
    float* o3 = out + ((size_t)tid + 3 * (size_t)nth) * 3;
    o3[0] = r3[0]; o3[1] = r3[1]; o3[2] = r3[2];

#undef COMPUTE
}

// ======================= r10 kernel as generic path =======================
__global__ __launch_bounds__(512) void fused_1pt(
    const float* __restrict__ x,
    const uint4* __restrict__ t2,
    const uint4* __restrict__ t3p,
    float* __restrict__ out,
    int npts)
{
    __shared__ uint4 s3[2 * T3D_N];
    #pragma unroll
    for (int i = threadIdx.x; i < 2 * T3D_N; i += 512) s3[i] = t3p[i];
    __syncthreads();

    int q = blockIdx.x * 512 + threadIdx.x;
    if (q >= npts) return;

    const float2 xv = ((const float2*)x)[q];
    float u = xv.x * (float)(RES_UP - 1);
    float v = xv.y * (float)(RES_UP - 1);
    int u0 = (int)u;
    int v0 = (int)v;
    float fu = u - (float)u0;
    float fv = v - (float)v0;

    uint4 g = t2[u0 * RES_UP + v0];

    const float S = (float)(RES_DN - 1) / 1023.0f;
    float wu0 = 1.0f - fu, wv0 = 1.0f - fv;
    float r00 = wu0 * wv0, r01 = wu0 * fv;
    float r10 = fu * wv0,  r11 = fu * fv;
    float key[3];
    #pragma unroll
    for (int l = 0; l < 3; ++l) {
        int s = l * 10;
        float d = uq10(g.x, s) * r00;
        d = fmaf(uq10(g.y, s), r01, d);
        d = fmaf(uq10(g.z, s), r10, d);
        d = fmaf(uq10(g.w, s), r11, d);
        key[l] = d * S;
    }
    int a0 = min((int)key[0], RES_DN - 2);
    int b0 = min((int)key[1], RES_DN - 2);
    int c0 = min((int)key[2], RES_DN - 2);
    float fa = key[0] - (float)a0;
    float fb = key[1] - (float)b0;
    float fc = key[2] - (float)c0;
    int si = (a0 * RES_DN + b0) * RES_DN + c0;

    uint4 qA = s3[si];
    uint4 qB = s3[si + T3D_N];

    const float D = 1.0f / 255.0f;
    float wb0 = 1.0f - fb, wc0 = 1.0f - fc;
    float q00 = wb0 * wc0, q01 = wb0 * fc;
    float q10 = fb * wc0,  q11 = fb * fc;
    float wa0D = (1.0f - fa) * D;
    float faD  = fa * D;
    const uint32_t* Aw = &qA.x;
    const uint32_t* Bw = &qB.x;
    float r[3];
    #pragma unroll
    for (int l = 0; l < 3; ++l) {
        uint32_t wA = Aw[l], wB = Bw[l];
        float dA = ub(wA, 0) * q00;
        dA = fmaf(ub(wA, 1), q01, dA);
        dA = fmaf(ub(wA, 2), q10, dA);
        dA = fmaf(ub(wA, 3), q11, dA);
        float dB = ub(wB, 0) * q00;
        dB = fmaf(ub(wB, 1), q01, dB);
        dB = fmaf(ub(wB, 2), q10, dB);
        dB = fmaf(ub(wB, 3), q11, dB);
        r[l] = wa0D * dA + faD * dB;
    }

    float* o = out + (size_t)q * 3;
    o[0] = r[0];
    o[1] = r[1];
    o[2] = r[2];
}

// Fallback (pure f32, unpacked tables) if workspace is tiny.
__device__ __forceinline__ float4 lerp4(const float4 a, const float4 b, const float t) {
    const float s = 1.0f - t;
    return make_float4(a.x * s + b.x * t, a.y * s + b.y * t, a.z * s + b.z * t, 0.0f);
}

__global__ __launch_bounds__(256) void fused_fallback(
    const float* __restrict__ x,
    const float* __restrict__ t2d,
    const float* __restrict__ t3d,
    float* __restrict__ out,
    int nquad)
{
    __shared__ float4 s3d[T3D_N];
    for (int i = threadIdx.x; i < T3D_N; i += blockDim.x) {
        float a = t3d[i * 3 + 0];
        float b = t3d[i * 3 + 1];
        float c = t3d[i * 3 + 2];
        s3d[i] = make_float4(fracf(a), fracf(b), fracf(c), 0.0f);
    }
    __syncthreads();

    const int stride = gridDim.x * blockDim.x;
    for (int q = blockIdx.x * blockDim.x + threadIdx.x; q < nquad; q += stride) {
        const float4 xa = ((const float4*)x)[q * 2 + 0];
        const float4 xb = ((const float4*)x)[q * 2 + 1];
        const float px[4] = {xa.x, xa.z, xb.x, xb.z};
        const float py[4] = {xa.y, xa.w, xb.y, xb.w};
        float res[12];

        #pragma unroll
        for (int k = 0; k < 4; ++k) {
            float u = px[k] * (float)(RES_UP - 1);
            float v = py[k] * (float)(RES_UP - 1);
            int u0 = min(max((int)floorf(u), 0), RES_UP - 2);
            int v0 = min(max((int)floorf(v), 0), RES_UP - 2);
            float fuu = u - (float)u0;
            float fvv = v - (float)v0;

            const float* p00 = t2d + ((size_t)u0 * RES_UP + v0) * 3;
            const float* p10 = p00 + RES_UP * 3;
            float key[3];
            #pragma unroll
            for (int l = 0; l < 3; ++l) {
                float c00 = fracf(p00[l]);
                float c01 = fracf(p00[3 + l]);
                float c10 = fracf(p10[l]);
                float c11 = fracf(p10[3 + l]);
                float c0 = c00 * (1.0f - fvv) + c01 * fvv;
                float c1 = c10 * (1.0f - fvv) + c11 * fvv;
                key[l] = c0 * (1.0f - fuu) + c1 * fuu;
            }

            float uu = key[0] * (float)(RES_DN - 1);
            float vv = key[1] * (float)(RES_DN - 1);
            float ww = key[2] * (float)(RES_DN - 1);
            int a0 = min(max((int)floorf(uu), 0), RES_DN - 2);
            int b0 = min(max((int)floorf(vv), 0), RES_DN - 2);
            int c0 = min(max((int)floorf(ww), 0), RES_DN - 2);
            float fa = uu - (float)a0;
            float fb = vv - (float)b0;
            float fc = ww - (float)c0;

            int sidx = (a0 * RES_DN + b0) * RES_DN + c0;
            float4 e00 = lerp4(s3d[sidx], s3d[sidx + 1], fc);
            float4 e01 = lerp4(s3d[sidx + RES_DN], s3d[sidx + RES_DN + 1], fc);
            float4 e10 = lerp4(s3d[sidx + 64], s3d[sidx + 65], fc);
            float4 e11 = lerp4(s3d[sidx + 72], s3d[sidx + 73], fc);
            float4 e = lerp4(lerp4(e00, e01, fb), lerp4(e10, e11, fb), fa);

            res[k * 3 + 0] = e.x;
            res[k * 3 + 1] = e.y;
            res[k * 3 + 2] = e.z;
        }

        float4* o = (float4*)(out + (size_t)q * 12);
        o[0] = make_float4(res[0], res[1], res[2],  res[3]);
        o[1] = make_float4(res[4], res[5], res[6],  res[7]);
        o[2] = make_float4(res[8], res[9], res[10], res[11]);
    }
}

extern "C" void kernel_launch(void* const* d_in, const int* in_sizes, int n_in,
                              void* d_out, int out_size, void* d_ws, size_t ws_size,
                              hipStream_t stream) {
    const float* x   = (const float*)d_in[0];
    const float* t2d = (const float*)d_in[1];
    const float* t3d = (const float*)d_in[2];
    float* out = (float*)d_out;

    int npts  = in_sizes[0] / 2;
    int nquad = npts / 4;

    const size_t need = (size_t)(T2D_N + 2 * T3D_N) * sizeof(uint4);  // 819200 B
    if (ws_size >= need) {
        uint4* ws2 = (uint4*)d_ws;
        uint4* ws3 = ws2 + T2D_N;
        repack_all<<<197, 256, 0, stream>>>(t2d, t3d, ws2, ws3);

        if ((npts & 3) == 0 && (npts / 4) % 512 == 0) {
            int nth = npts / 4;
            fused_mlp4<<<nth / 512, 512, 0, stream>>>(x, ws2, ws3, out, nth);
        } else {
            fused_1pt<<<(npts + 511) / 512, 512, 0, stream>>>(x, ws2, ws3, out, npts);
        }
    } else {
        fused_fallback<<<2048, 256, 0, stream>>>(x, t2d, t3d, out, nquad);
    }
}